// Round 9
// baseline (209.462 us; speedup 1.0000x reference)
//
#include <hip/hip_runtime.h>
#include <math.h>

#define NF 64
#define SHIFT 9              // 512 nodes per dst-bucket
#define BSZ 512
#define MAXNB 256            // bucket arrays sized for <=256 buckets
#define CHUNK 4096           // edges per kb_bin block
#define SL1 4                // slices per bucket, layer-1 agg
#define SL2 4                // slices per bucket, layer-2 agg

// ---------------------------------------------------------------------------
// Bucket histogram of dst>>SHIFT (LDS-aggregated).
// ---------------------------------------------------------------------------
__global__ __launch_bounds__(256) void kb_hist(
    const int* __restrict__ ei, int* __restrict__ bhist, int E, int nb) {
    __shared__ int h[MAXNB];
    int t = threadIdx.x;
    if (t < nb) h[t] = 0;
    __syncthreads();
    int stride = gridDim.x * 256;
    for (int e = blockIdx.x * 256 + t; e < E; e += stride)
        atomicAdd(&h[((unsigned)ei[E + e]) >> SHIFT], 1);
    __syncthreads();
    if (t < nb && h[t]) atomicAdd(&bhist[t], h[t]);
}

// ---------------------------------------------------------------------------
// Exclusive scan of bucket counts -> bbase (+ cursor copy bcur).
// ---------------------------------------------------------------------------
__global__ __launch_bounds__(256) void kb_scan(
    const int* __restrict__ bhist, int* __restrict__ bbase,
    int* __restrict__ bcur, int nb) {
    __shared__ int s[256];
    int t = threadIdx.x;
    int v = (t < nb) ? bhist[t] : 0;
    s[t] = v;
    __syncthreads();
    for (int off = 1; off < 256; off <<= 1) {
        int a = (t >= off) ? s[t - off] : 0;
        __syncthreads();
        s[t] += a;
        __syncthreads();
    }
    if (t < nb) { bbase[t] = s[t] - v; bcur[t] = s[t] - v; }
    if (t == nb - 1) bbase[nb] = s[t];      // total = E
}

// ---------------------------------------------------------------------------
// Bin edges by dst-bucket with in-LDS local sort; flush each bucket's run as
// a CONTIGUOUS global write. Packed edge: (d_local<<17)|src  (N < 2^17).
// ---------------------------------------------------------------------------
__global__ __launch_bounds__(256) void kb_bin(
    const int* __restrict__ ei, int* __restrict__ bcur,
    int* __restrict__ ebin, int E, int nb) {
    __shared__ int spair[CHUNK];
    __shared__ unsigned short sbkt[CHUNK];
    __shared__ int h[MAXNB], sb[MAXNB], lcur[MAXNB], goff[MAXNB];
    __shared__ int ss[256];
    int t = threadIdx.x;
    int e0 = blockIdx.x * CHUNK;
    if (t < nb) h[t] = 0;
    __syncthreads();

    int pv[CHUNK / 256], pb[CHUNK / 256];
#pragma unroll
    for (int k = 0; k < CHUNK / 256; ++k) {
        int e = e0 + k * 256 + t;
        if (e < E) {
            int sv = ei[e];
            unsigned d = (unsigned)ei[E + e];
            int b = d >> SHIFT;
            pb[k] = b;
            pv[k] = (int)(((d & (BSZ - 1)) << 17) | (unsigned)sv);
            atomicAdd(&h[b], 1);
        } else pb[k] = -1;
    }
    __syncthreads();
    {   // exclusive scan h -> sb (+ cursor)
        int v = (t < nb) ? h[t] : 0;
        ss[t] = v;
        __syncthreads();
        for (int off = 1; off < 256; off <<= 1) {
            int a = (t >= off) ? ss[t - off] : 0;
            __syncthreads();
            ss[t] += a;
            __syncthreads();
        }
        if (t < nb) { sb[t] = ss[t] - v; lcur[t] = ss[t] - v; }
    }
    __syncthreads();
#pragma unroll
    for (int k = 0; k < CHUNK / 256; ++k) {
        if (pb[k] >= 0) {
            int pos = atomicAdd(&lcur[pb[k]], 1);
            spair[pos] = pv[k];
            sbkt[pos] = (unsigned short)pb[k];
        }
    }
    __syncthreads();
    if (t < nb && h[t] > 0) goff[t] = atomicAdd(&bcur[t], h[t]);
    __syncthreads();
    int M = min(CHUNK, E - e0);
    for (int i = t; i < M; i += 256) {
        int b = sbkt[i];
        ebin[goff[b] + i - sb[b]] = spair[i];
    }
}

// ---------------------------------------------------------------------------
// Composite matrices (whole net collapsed to [64 x 8] + 4 consts).
// comp[k*8+..] = Mp.{01},Np.{01},Mq.{01},Nq.{01}; comp[512..515] = biases.
// ---------------------------------------------------------------------------
__global__ __launch_bounds__(256) void k_compose(
    const float* __restrict__ Wl1, const float* __restrict__ bl1,
    const float* __restrict__ Wr1, const float* __restrict__ Wl2,
    const float* __restrict__ Wr2, float* __restrict__ comp) {
    int t = threadIdx.x;
    int m = t >> 6;          // 0:Mp 1:Np 2:Mq 3:Nq
    int k = t & 63;
    const float* W1 = (m == 0 || m == 2) ? Wl1 : Wr1;
    const float* W2 = (m < 2) ? Wl2 : Wr2;
    float a0 = 0.f, a1 = 0.f;
    for (int o = 0; o < NF; ++o) {
        float w1 = W1[o * NF + k];
        a0 = fmaf(W2[o], w1, a0);
        a1 = fmaf(W2[NF + o], w1, a1);
    }
    comp[k * 8 + 2 * m]     = a0;
    comp[k * 8 + 2 * m + 1] = a1;
    if (t < 4) {
        const float* W2c = (t < 2) ? Wl2 : Wr2;
        int c = t & 1;
        float s = 0.f;
        for (int o = 0; o < NF; ++o) s = fmaf(bl1[o], W2c[c * NF + o], s);
        comp[512 + t] = s;
    }
}

// ---------------------------------------------------------------------------
// Project nodes: ac[node]=(a0,a1,c0,c1) (1.6 MB, the only per-edge operand);
// bd[node]=self terms + bias consts.
// ---------------------------------------------------------------------------
__global__ __launch_bounds__(256) void k_project(
    const float4* __restrict__ x4, const float* __restrict__ comp,
    float4* __restrict__ ac, float4* __restrict__ bd, int N) {
    int node = blockIdx.x * 256 + threadIdx.x;
    if (node >= N) return;
    float a0 = 0.f, a1 = 0.f, b0 = 0.f, b1 = 0.f;
    float c0 = 0.f, c1 = 0.f, d0 = 0.f, d1 = 0.f;
#pragma unroll
    for (int kk = 0; kk < 16; ++kk) {
        float4 xv = x4[(size_t)node * 16 + kk];
        const float xs[4] = {xv.x, xv.y, xv.z, xv.w};
#pragma unroll
        for (int j = 0; j < 4; ++j) {
            float xj = xs[j];
            const float* c8 = comp + (kk * 4 + j) * 8;
            a0 = fmaf(xj, c8[0], a0); a1 = fmaf(xj, c8[1], a1);
            b0 = fmaf(xj, c8[2], b0); b1 = fmaf(xj, c8[3], b1);
            c0 = fmaf(xj, c8[4], c0); c1 = fmaf(xj, c8[5], c1);
            d0 = fmaf(xj, c8[6], d0); d1 = fmaf(xj, c8[7], d1);
        }
    }
    ac[node] = make_float4(a0, a1, c0, c1);
    bd[node] = make_float4(b0 + comp[512], b1 + comp[513],
                           d0 + comp[514], d1 + comp[515]);
}

// ---------------------------------------------------------------------------
// Layer-1 aggregation, SL1 slice-blocks per bucket. LDS accumulator padded
// to stride 5 (coprime with 32 banks -> conflict-free ds_add_f32). Flush
// nonzero rows with CONTIGUOUS global atomics (TCC-mergeable).
// ---------------------------------------------------------------------------
__global__ __launch_bounds__(512) void k_agg1s(
    const int* __restrict__ ebin, const int* __restrict__ bbase,
    const float4* __restrict__ ac,
    float* __restrict__ acc, float* __restrict__ dega, int N) {
    __shared__ float sa[BSZ * 5];
    __shared__ int ldeg[BSZ];
    int b = blockIdx.x / SL1, sl = blockIdx.x % SL1;
    int t = threadIdx.x;
    sa[t * 5 + 0] = 0.f; sa[t * 5 + 1] = 0.f;
    sa[t * 5 + 2] = 0.f; sa[t * 5 + 3] = 0.f;
    ldeg[t] = 0;
    __syncthreads();
    int g0 = bbase[b], cnt = bbase[b + 1] - g0;
    int sbeg = g0 + (int)(((long long)cnt * sl) / SL1);
    int send = g0 + (int)(((long long)cnt * (sl + 1)) / SL1);
    for (int i = sbeg + t; i < send; i += 512) {
        int pv = ebin[i];
        int dl = pv >> 17;
        float4 v = ac[pv & 0x1FFFF];
        atomicAdd(&sa[dl * 5 + 0], v.x);
        atomicAdd(&sa[dl * 5 + 1], v.y);
        atomicAdd(&sa[dl * 5 + 2], v.z);
        atomicAdd(&sa[dl * 5 + 3], v.w);
        atomicAdd(&ldeg[dl], 1);
    }
    __syncthreads();
    int node = (b << SHIFT) + t;
    if (node < N && ldeg[t] > 0) {
        atomicAdd(&acc[(size_t)node * 4 + 0], sa[t * 5 + 0]);
        atomicAdd(&acc[(size_t)node * 4 + 1], sa[t * 5 + 1]);
        atomicAdd(&acc[(size_t)node * 4 + 2], sa[t * 5 + 2]);
        atomicAdd(&acc[(size_t)node * 4 + 3], sa[t * 5 + 3]);
        atomicAdd(&dega[node], (float)ldeg[t]);
    }
}

// ---------------------------------------------------------------------------
// Combine partials: p,q = acc/deg + bd ; deg = max(dega,1). Thread per node.
// ---------------------------------------------------------------------------
__global__ __launch_bounds__(256) void k_combine(
    const float4* __restrict__ acc, const float* __restrict__ dega,
    const float4* __restrict__ bd, float2* __restrict__ p,
    float2* __restrict__ q, float* __restrict__ deg, int N) {
    int node = blockIdx.x * 256 + threadIdx.x;
    if (node >= N) return;
    float4 s = acc[node];
    float4 b = bd[node];
    float dg = fmaxf(dega[node], 1.f);
    float inv = 1.f / dg;
    p[node] = make_float2(fmaf(s.x, inv, b.x), fmaf(s.y, inv, b.y));
    q[node] = make_float2(fmaf(s.z, inv, b.z), fmaf(s.w, inv, b.w));
    deg[node] = dg;
}

// ---------------------------------------------------------------------------
// Layer-2 aggregation, SL2 slice-blocks per bucket; LDS stride 3 (coprime
// with 32). Flush nonzero rows with contiguous global atomics into acc2.
// ---------------------------------------------------------------------------
__global__ __launch_bounds__(512) void k_agg2s(
    const int* __restrict__ ebin, const int* __restrict__ bbase,
    const float2* __restrict__ p, float* __restrict__ acc2, int N) {
    __shared__ float sa[BSZ * 3];
    __shared__ int touched[BSZ];
    int b = blockIdx.x / SL2, sl = blockIdx.x % SL2;
    int t = threadIdx.x;
    sa[t * 3 + 0] = 0.f; sa[t * 3 + 1] = 0.f;
    touched[t] = 0;
    __syncthreads();
    int g0 = bbase[b], cnt = bbase[b + 1] - g0;
    int sbeg = g0 + (int)(((long long)cnt * sl) / SL2);
    int send = g0 + (int)(((long long)cnt * (sl + 1)) / SL2);
    for (int i = sbeg + t; i < send; i += 512) {
        int pv = ebin[i];
        int dl = pv >> 17;
        float2 v = p[pv & 0x1FFFF];
        atomicAdd(&sa[dl * 3 + 0], v.x);
        atomicAdd(&sa[dl * 3 + 1], v.y);
        touched[dl] = 1;
    }
    __syncthreads();
    int node = (b << SHIFT) + t;
    if (node < N && touched[t]) {
        atomicAdd(&acc2[(size_t)node * 2 + 0], sa[t * 3 + 0]);
        atomicAdd(&acc2[(size_t)node * 2 + 1], sa[t * 3 + 1]);
    }
}

// ---------------------------------------------------------------------------
// Final: logits = acc2/deg + bl2 + q ; out = log_softmax. Thread per node.
// ---------------------------------------------------------------------------
__global__ __launch_bounds__(256) void k_final(
    const float2* __restrict__ acc2, const float* __restrict__ deg,
    const float2* __restrict__ q, const float* __restrict__ bl2,
    float2* __restrict__ out, int N) {
    int node = blockIdx.x * 256 + threadIdx.x;
    if (node >= N) return;
    float2 a2 = acc2[node];
    float2 qv = q[node];
    float inv = 1.f / deg[node];
    float l0 = fmaf(a2.x, inv, bl2[0] + qv.x);
    float l1 = fmaf(a2.y, inv, bl2[1] + qv.y);
    float m = fmaxf(l0, l1);
    float lse = m + logf(expf(l0 - m) + expf(l1 - m));
    out[node] = make_float2(l0 - lse, l1 - lse);
}

// ---------------------------------------------------------------------------
extern "C" void kernel_launch(void* const* d_in, const int* in_sizes, int n_in,
                              void* d_out, int out_size, void* d_ws, size_t ws_size,
                              hipStream_t stream) {
    const float* x   = (const float*)d_in[0];
    const int*   ei  = (const int*)d_in[1];
    const float* Wl1 = (const float*)d_in[2];
    const float* bl1 = (const float*)d_in[3];
    const float* Wr1 = (const float*)d_in[4];
    const float* Wl2 = (const float*)d_in[5];
    const float* bl2 = (const float*)d_in[6];
    const float* Wr2 = (const float*)d_in[7];
    float* out = (float*)d_out;

    int N = in_sizes[0] / NF;     // 100000 (< 2^17 required by packing)
    int E = in_sizes[1] / 2;      // 1600000
    int nb = (N + BSZ - 1) >> SHIFT;   // 196 buckets

    // Workspace: ints [ebin:E | bhist:256 | bbase:257 | bcur:256 | pad:3]
    //            floats [acc:4N | dega:N | acc2:2N]   <- zeroed (7N)
    //                   [comp:516 | ac:4N | bd:4N | p:2N | q:2N | deg:N]
    int* wsi    = (int*)d_ws;
    int* ebin   = wsi;
    int* bhist  = wsi + E;
    int* bbase  = bhist + 256;
    int* bcur   = bbase + 257;
    float* acc  = (float*)(bcur + 256 + 3);   // 16B-aligned
    float* dega = acc + 4 * (size_t)N;
    float* acc2 = dega + N;
    float* comp = acc2 + 2 * (size_t)N;
    float* ac   = comp + 516;
    float* bd   = ac + 4 * (size_t)N;
    float* p    = bd + 4 * (size_t)N;
    float* q    = p + 2 * (size_t)N;
    float* deg  = q + 2 * (size_t)N;

    hipMemsetAsync(bhist, 0, 256 * sizeof(int), stream);
    hipMemsetAsync(acc, 0, 7 * (size_t)N * sizeof(float), stream);

    int nbN = (N + 255) / 256;

    kb_hist<<<256, 256, 0, stream>>>(ei, bhist, E, nb);
    kb_scan<<<1, 256, 0, stream>>>(bhist, bbase, bcur, nb);
    kb_bin <<<(E + CHUNK - 1) / CHUNK, 256, 0, stream>>>(ei, bcur, ebin, E, nb);

    k_compose<<<1, 256, 0, stream>>>(Wl1, bl1, Wr1, Wl2, Wr2, comp);
    k_project<<<nbN, 256, 0, stream>>>((const float4*)x, comp,
                                       (float4*)ac, (float4*)bd, N);

    k_agg1s<<<nb * SL1, 512, 0, stream>>>(ebin, bbase, (const float4*)ac,
                                          acc, dega, N);
    k_combine<<<nbN, 256, 0, stream>>>((const float4*)acc, dega,
                                       (const float4*)bd, (float2*)p,
                                       (float2*)q, deg, N);
    k_agg2s<<<nb * SL2, 512, 0, stream>>>(ebin, bbase, (const float2*)p,
                                          acc2, N);
    k_final<<<nbN, 256, 0, stream>>>((const float2*)acc2, deg,
                                     (const float2*)q, bl2,
                                     (float2*)out, N);
}

// Round 10
// 172.068 us; speedup vs baseline: 1.2173x; 1.2173x over previous
//
#include <hip/hip_runtime.h>
#include <math.h>

#define NF 64
#define SHIFT 9              // 512 nodes per dst-bucket
#define BSZ 512
#define MAXNB 256            // bucket arrays sized for <=256 buckets
#define CHUNK 4096           // edges per kb_bin block

// ---------------------------------------------------------------------------
// Bucket histogram of dst>>SHIFT (LDS-aggregated).
// ---------------------------------------------------------------------------
__global__ __launch_bounds__(256) void kb_hist(
    const int* __restrict__ ei, int* __restrict__ bhist, int E, int nb) {
    __shared__ int h[MAXNB];
    int t = threadIdx.x;
    if (t < nb) h[t] = 0;
    __syncthreads();
    int stride = gridDim.x * 256;
    for (int e = blockIdx.x * 256 + t; e < E; e += stride)
        atomicAdd(&h[((unsigned)ei[E + e]) >> SHIFT], 1);
    __syncthreads();
    if (t < nb && h[t]) atomicAdd(&bhist[t], h[t]);
}

// ---------------------------------------------------------------------------
// Exclusive scan of bucket counts -> bbase (+ cursor copy bcur).
// ---------------------------------------------------------------------------
__global__ __launch_bounds__(256) void kb_scan(
    const int* __restrict__ bhist, int* __restrict__ bbase,
    int* __restrict__ bcur, int nb) {
    __shared__ int s[256];
    int t = threadIdx.x;
    int v = (t < nb) ? bhist[t] : 0;
    s[t] = v;
    __syncthreads();
    for (int off = 1; off < 256; off <<= 1) {
        int a = (t >= off) ? s[t - off] : 0;
        __syncthreads();
        s[t] += a;
        __syncthreads();
    }
    if (t < nb) { bbase[t] = s[t] - v; bcur[t] = s[t] - v; }
    if (t == nb - 1) bbase[nb] = s[t];      // total = E
}

// ---------------------------------------------------------------------------
// Bin edges by dst-bucket with in-LDS local sort; flush each bucket's run as
// a CONTIGUOUS global write. Packed edge: (d_local<<17)|src  (N < 2^17).
// ---------------------------------------------------------------------------
__global__ __launch_bounds__(256) void kb_bin(
    const int* __restrict__ ei, int* __restrict__ bcur,
    int* __restrict__ ebin, int E, int nb) {
    __shared__ int spair[CHUNK];
    __shared__ unsigned short sbkt[CHUNK];
    __shared__ int h[MAXNB], sb[MAXNB], lcur[MAXNB], goff[MAXNB];
    __shared__ int ss[256];
    int t = threadIdx.x;
    int e0 = blockIdx.x * CHUNK;
    if (t < nb) h[t] = 0;
    __syncthreads();

    int pv[CHUNK / 256], pb[CHUNK / 256];
#pragma unroll
    for (int k = 0; k < CHUNK / 256; ++k) {
        int e = e0 + k * 256 + t;
        if (e < E) {
            int sv = ei[e];
            unsigned d = (unsigned)ei[E + e];
            int b = d >> SHIFT;
            pb[k] = b;
            pv[k] = (int)(((d & (BSZ - 1)) << 17) | (unsigned)sv);
            atomicAdd(&h[b], 1);
        } else pb[k] = -1;
    }
    __syncthreads();
    {   // exclusive scan h -> sb (+ cursor)
        int v = (t < nb) ? h[t] : 0;
        ss[t] = v;
        __syncthreads();
        for (int off = 1; off < 256; off <<= 1) {
            int a = (t >= off) ? ss[t - off] : 0;
            __syncthreads();
            ss[t] += a;
            __syncthreads();
        }
        if (t < nb) { sb[t] = ss[t] - v; lcur[t] = ss[t] - v; }
    }
    __syncthreads();
#pragma unroll
    for (int k = 0; k < CHUNK / 256; ++k) {
        if (pb[k] >= 0) {
            int pos = atomicAdd(&lcur[pb[k]], 1);
            spair[pos] = pv[k];
            sbkt[pos] = (unsigned short)pb[k];
        }
    }
    __syncthreads();
    if (t < nb && h[t] > 0) goff[t] = atomicAdd(&bcur[t], h[t]);
    __syncthreads();
    int M = min(CHUNK, E - e0);
    for (int i = t; i < M; i += 256) {
        int b = sbkt[i];
        ebin[goff[b] + i - sb[b]] = spair[i];
    }
}

// ---------------------------------------------------------------------------
// Per-bucket final counting sort (round-6 proven code): one block per bucket;
// scatter stays inside a ~33 KB L2-hot region. Emits srt (src ordered by
// dst), deg[] and base[] (CSR offsets). 2 int LDS atomics per edge — the
// minimum; both aggregation passes are then atomic-free.
// ---------------------------------------------------------------------------
__global__ __launch_bounds__(512) void kb_sort(
    const int* __restrict__ ebin, const int* __restrict__ bbase,
    int* __restrict__ srt, int* __restrict__ deg, int* __restrict__ base,
    int N, int nb) {
    __shared__ int h[BSZ], lb[BSZ], ss[BSZ];
    int b = blockIdx.x;
    int t = threadIdx.x;
    int gstart = bbase[b];
    int cnt = bbase[b + 1] - gstart;
    int n0 = b << SHIFT;
    int nn = min(BSZ, N - n0);
    h[t] = 0;
    __syncthreads();
    for (int i = t; i < cnt; i += 512)
        atomicAdd(&h[ebin[gstart + i] >> 17], 1);
    __syncthreads();
    int v = h[t];
    ss[t] = v;
    __syncthreads();
    for (int off = 1; off < 512; off <<= 1) {
        int a = (t >= off) ? ss[t - off] : 0;
        __syncthreads();
        ss[t] += a;
        __syncthreads();
    }
    lb[t] = ss[t] - v;                      // exclusive within bucket
    if (t < nn) { deg[n0 + t] = v; base[n0 + t] = gstart + lb[t]; }
    __syncthreads();
    h[t] = 0;                               // reuse as per-node cursor
    __syncthreads();
    for (int i = t; i < cnt; i += 512) {
        int pv = ebin[gstart + i];
        int dl = pv >> 17;
        int pos = atomicAdd(&h[dl], 1);
        srt[gstart + lb[dl] + pos] = pv & 0x1FFFF;
    }
}

// ---------------------------------------------------------------------------
// Composite matrices (whole net collapsed to [64 x 8] + 4 consts).
// comp[k*8+..] = Mp.{01},Np.{01},Mq.{01},Nq.{01}; comp[512..515] = biases.
// ---------------------------------------------------------------------------
__global__ __launch_bounds__(256) void k_compose(
    const float* __restrict__ Wl1, const float* __restrict__ bl1,
    const float* __restrict__ Wr1, const float* __restrict__ Wl2,
    const float* __restrict__ Wr2, float* __restrict__ comp) {
    int t = threadIdx.x;
    int m = t >> 6;          // 0:Mp 1:Np 2:Mq 3:Nq
    int k = t & 63;
    const float* W1 = (m == 0 || m == 2) ? Wl1 : Wr1;
    const float* W2 = (m < 2) ? Wl2 : Wr2;
    float a0 = 0.f, a1 = 0.f;
    for (int o = 0; o < NF; ++o) {
        float w1 = W1[o * NF + k];
        a0 = fmaf(W2[o], w1, a0);
        a1 = fmaf(W2[NF + o], w1, a1);
    }
    comp[k * 8 + 2 * m]     = a0;
    comp[k * 8 + 2 * m + 1] = a1;
    if (t < 4) {
        const float* W2c = (t < 2) ? Wl2 : Wr2;
        int c = t & 1;
        float s = 0.f;
        for (int o = 0; o < NF; ++o) s = fmaf(bl1[o], W2c[c * NF + o], s);
        comp[512 + t] = s;
    }
}

// ---------------------------------------------------------------------------
// Project nodes: ac[node]=(a0,a1,c0,c1) (1.6 MB, the only per-edge operand);
// bd[node]=self terms + bias consts.
// ---------------------------------------------------------------------------
__global__ __launch_bounds__(256) void k_project(
    const float4* __restrict__ x4, const float* __restrict__ comp,
    float4* __restrict__ ac, float4* __restrict__ bd, int N) {
    int node = blockIdx.x * 256 + threadIdx.x;
    if (node >= N) return;
    float a0 = 0.f, a1 = 0.f, b0 = 0.f, b1 = 0.f;
    float c0 = 0.f, c1 = 0.f, d0 = 0.f, d1 = 0.f;
#pragma unroll
    for (int kk = 0; kk < 16; ++kk) {
        float4 xv = x4[(size_t)node * 16 + kk];
        const float xs[4] = {xv.x, xv.y, xv.z, xv.w};
#pragma unroll
        for (int j = 0; j < 4; ++j) {
            float xj = xs[j];
            const float* c8 = comp + (kk * 4 + j) * 8;
            a0 = fmaf(xj, c8[0], a0); a1 = fmaf(xj, c8[1], a1);
            b0 = fmaf(xj, c8[2], b0); b1 = fmaf(xj, c8[3], b1);
            c0 = fmaf(xj, c8[4], c0); c1 = fmaf(xj, c8[5], c1);
            d0 = fmaf(xj, c8[6], d0); d1 = fmaf(xj, c8[7], d1);
        }
    }
    ac[node] = make_float4(a0, a1, c0, c1);
    bd[node] = make_float4(b0 + comp[512], b1 + comp[513],
                           d0 + comp[514], d1 + comp[515]);
}

// ---------------------------------------------------------------------------
// Layer-1 aggregation over CSR, ATOMIC-FREE: 4 lanes per node, each lane
// gathers a quarter of the node's ac[src] segment into registers, quad
// shfl-reduce, lane 0 writes p,q. No LDS at all.
// ---------------------------------------------------------------------------
__global__ __launch_bounds__(256) void k_agg1c(
    const int* __restrict__ srt, const int* __restrict__ base,
    const int* __restrict__ deg, const float4* __restrict__ ac,
    const float4* __restrict__ bd, float2* __restrict__ p,
    float2* __restrict__ q, int N) {
    int tid = blockIdx.x * 256 + threadIdx.x;
    int node = tid >> 2, c = tid & 3;
    if (node >= N) return;
    int b0 = base[node];
    int dg = deg[node];
    float a0 = 0.f, a1 = 0.f, c0 = 0.f, c1 = 0.f;
    for (int j = c; j < dg; j += 4) {
        float4 v = ac[srt[b0 + j]];
        a0 += v.x; a1 += v.y; c0 += v.z; c1 += v.w;
    }
    a0 += __shfl_xor(a0, 1, 64); a0 += __shfl_xor(a0, 2, 64);
    a1 += __shfl_xor(a1, 1, 64); a1 += __shfl_xor(a1, 2, 64);
    c0 += __shfl_xor(c0, 1, 64); c0 += __shfl_xor(c0, 2, 64);
    c1 += __shfl_xor(c1, 1, 64); c1 += __shfl_xor(c1, 2, 64);
    if (c == 0) {
        float inv = 1.f / (float)(dg > 1 ? dg : 1);
        float4 b = bd[node];
        p[node] = make_float2(fmaf(a0, inv, b.x), fmaf(a1, inv, b.y));
        q[node] = make_float2(fmaf(c0, inv, b.z), fmaf(c1, inv, b.w));
    }
}

// ---------------------------------------------------------------------------
// Layer-2 aggregation + epilogue, ATOMIC-FREE: 2 lanes per node over p,
// pair shfl-reduce, lane 0 does log_softmax and writes out.
// ---------------------------------------------------------------------------
__global__ __launch_bounds__(256) void k_agg2c(
    const int* __restrict__ srt, const int* __restrict__ base,
    const int* __restrict__ deg, const float2* __restrict__ p,
    const float2* __restrict__ q, const float* __restrict__ bl2,
    float2* __restrict__ out, int N) {
    int tid = blockIdx.x * 256 + threadIdx.x;
    int node = tid >> 1, c = tid & 1;
    if (node >= N) return;
    int b0 = base[node];
    int dg = deg[node];
    float s0 = 0.f, s1 = 0.f;
    for (int j = c; j < dg; j += 2) {
        float2 v = p[srt[b0 + j]];
        s0 += v.x; s1 += v.y;
    }
    s0 += __shfl_xor(s0, 1, 64);
    s1 += __shfl_xor(s1, 1, 64);
    if (c == 0) {
        float inv = 1.f / (float)(dg > 1 ? dg : 1);
        float2 qv = q[node];
        float l0 = fmaf(s0, inv, bl2[0] + qv.x);
        float l1 = fmaf(s1, inv, bl2[1] + qv.y);
        float m = fmaxf(l0, l1);
        float lse = m + logf(expf(l0 - m) + expf(l1 - m));
        out[node] = make_float2(l0 - lse, l1 - lse);
    }
}

// ---------------------------------------------------------------------------
extern "C" void kernel_launch(void* const* d_in, const int* in_sizes, int n_in,
                              void* d_out, int out_size, void* d_ws, size_t ws_size,
                              hipStream_t stream) {
    const float* x   = (const float*)d_in[0];
    const int*   ei  = (const int*)d_in[1];
    const float* Wl1 = (const float*)d_in[2];
    const float* bl1 = (const float*)d_in[3];
    const float* Wr1 = (const float*)d_in[4];
    const float* Wl2 = (const float*)d_in[5];
    const float* bl2 = (const float*)d_in[6];
    const float* Wr2 = (const float*)d_in[7];
    float* out = (float*)d_out;

    int N = in_sizes[0] / NF;     // 100000 (< 2^17 required by packing)
    int E = in_sizes[1] / 2;      // 1600000
    int nb = (N + BSZ - 1) >> SHIFT;   // 196 buckets

    // Workspace: ints [ebin:E | srt:E | deg:N | base:N | bhist:256 |
    //                  bbase:257 | bcur:256 | pad:3]
    //            floats [comp:516 | ac:4N | bd:4N | p:2N | q:2N]
    int* wsi    = (int*)d_ws;
    int* ebin   = wsi;
    int* srt    = wsi + E;
    int* deg    = wsi + 2 * (size_t)E;
    int* base   = deg + N;
    int* bhist  = base + N;
    int* bbase  = bhist + 256;
    int* bcur   = bbase + 257;
    float* comp = (float*)(bcur + 256 + 3);   // 16B-aligned
    float* ac   = comp + 516;
    float* bd   = ac + 4 * (size_t)N;
    float* p    = bd + 4 * (size_t)N;
    float* q    = p + 2 * (size_t)N;

    hipMemsetAsync(bhist, 0, 256 * sizeof(int), stream);

    int nbN = (N + 255) / 256;

    kb_hist<<<256, 256, 0, stream>>>(ei, bhist, E, nb);
    kb_scan<<<1, 256, 0, stream>>>(bhist, bbase, bcur, nb);
    kb_bin <<<(E + CHUNK - 1) / CHUNK, 256, 0, stream>>>(ei, bcur, ebin, E, nb);
    kb_sort<<<nb, 512, 0, stream>>>(ebin, bbase, srt, deg, base, N, nb);

    k_compose<<<1, 256, 0, stream>>>(Wl1, bl1, Wr1, Wl2, Wr2, comp);
    k_project<<<nbN, 256, 0, stream>>>((const float4*)x, comp,
                                       (float4*)ac, (float4*)bd, N);

    k_agg1c<<<(4 * N + 255) / 256, 256, 0, stream>>>(srt, base, deg,
                                                     (const float4*)ac,
                                                     (const float4*)bd,
                                                     (float2*)p, (float2*)q, N);
    k_agg2c<<<(2 * N + 255) / 256, 256, 0, stream>>>(srt, base, deg,
                                                     (const float2*)p,
                                                     (const float2*)q, bl2,
                                                     (float2*)out, N);
}

// Round 11
// 156.936 us; speedup vs baseline: 1.3347x; 1.0964x over previous
//
#include <hip/hip_runtime.h>
#include <math.h>

#define NF 64
#define SHIFT 9              // 512 nodes per dst-bucket
#define BSZ 512
#define MAXNB 256            // bucket arrays sized for <=256 buckets
#define CHUNK 4096           // edges per kb_bin block
#define CAP 12288            // LDS capacity (edges) per bucket in kb_sortagg

// ---------------------------------------------------------------------------
// Bucket histogram of dst>>SHIFT (LDS-aggregated, int4-vectorized loads).
// ---------------------------------------------------------------------------
__global__ __launch_bounds__(256) void kb_hist(
    const int* __restrict__ ei, int* __restrict__ bhist, int E, int nb) {
    __shared__ int h[MAXNB];
    int t = threadIdx.x;
    if (t < nb) h[t] = 0;
    __syncthreads();
    int stride = gridDim.x * 256;
    const int4* d4 = (const int4*)(ei + E);
    int n4 = E >> 2;
    for (int i = blockIdx.x * 256 + t; i < n4; i += stride) {
        int4 v = d4[i];
        atomicAdd(&h[((unsigned)v.x) >> SHIFT], 1);
        atomicAdd(&h[((unsigned)v.y) >> SHIFT], 1);
        atomicAdd(&h[((unsigned)v.z) >> SHIFT], 1);
        atomicAdd(&h[((unsigned)v.w) >> SHIFT], 1);
    }
    for (int e = (n4 << 2) + blockIdx.x * 256 + t; e < E; e += stride)
        atomicAdd(&h[((unsigned)ei[E + e]) >> SHIFT], 1);
    __syncthreads();
    if (t < nb && h[t]) atomicAdd(&bhist[t], h[t]);
}

// ---------------------------------------------------------------------------
// Exclusive scan of bucket counts -> bbase (+ cursor copy bcur).
// ---------------------------------------------------------------------------
__global__ __launch_bounds__(256) void kb_scan(
    const int* __restrict__ bhist, int* __restrict__ bbase,
    int* __restrict__ bcur, int nb) {
    __shared__ int s[256];
    int t = threadIdx.x;
    int v = (t < nb) ? bhist[t] : 0;
    s[t] = v;
    __syncthreads();
    for (int off = 1; off < 256; off <<= 1) {
        int a = (t >= off) ? s[t - off] : 0;
        __syncthreads();
        s[t] += a;
        __syncthreads();
    }
    if (t < nb) { bbase[t] = s[t] - v; bcur[t] = s[t] - v; }
    if (t == nb - 1) bbase[nb] = s[t];      // total = E
}

// ---------------------------------------------------------------------------
// Bin edges by dst-bucket with in-LDS local sort; flush each bucket's run as
// a CONTIGUOUS global write. int4-vectorized edge loads (16 edges/thread).
// Packed edge: (d_local<<17)|src  (N < 2^17).
// ---------------------------------------------------------------------------
__global__ __launch_bounds__(256) void kb_bin(
    const int* __restrict__ ei, int* __restrict__ bcur,
    int* __restrict__ ebin, int E, int nb) {
    __shared__ int spair[CHUNK];
    __shared__ unsigned short sbkt[CHUNK];
    __shared__ int h[MAXNB], sb[MAXNB], lcur[MAXNB], goff[MAXNB];
    __shared__ int ss[256];
    int t = threadIdx.x;
    int e0 = blockIdx.x * CHUNK;
    if (t < nb) h[t] = 0;
    __syncthreads();

    const int4* s4 = (const int4*)ei;
    const int4* d4 = (const int4*)(ei + E);
    int pv[16], pb[16];
#pragma unroll
    for (int k = 0; k < 4; ++k) {
        int i4 = (e0 >> 2) + k * 256 + t;
        int ebase = i4 << 2;
        if (ebase < E) {
            int4 sv = s4[i4];
            int4 dv = d4[i4];
            const int svl[4] = {sv.x, sv.y, sv.z, sv.w};
            const int dvl[4] = {dv.x, dv.y, dv.z, dv.w};
#pragma unroll
            for (int l = 0; l < 4; ++l) {
                int e = ebase + l;
                if (e < E) {
                    unsigned d = (unsigned)dvl[l];
                    int b = d >> SHIFT;
                    pb[k * 4 + l] = b;
                    pv[k * 4 + l] =
                        (int)(((d & (BSZ - 1)) << 17) | (unsigned)svl[l]);
                    atomicAdd(&h[b], 1);
                } else pb[k * 4 + l] = -1;
            }
        } else {
#pragma unroll
            for (int l = 0; l < 4; ++l) pb[k * 4 + l] = -1;
        }
    }
    __syncthreads();
    {   // exclusive scan h -> sb (+ cursor)
        int v = (t < nb) ? h[t] : 0;
        ss[t] = v;
        __syncthreads();
        for (int off = 1; off < 256; off <<= 1) {
            int a = (t >= off) ? ss[t - off] : 0;
            __syncthreads();
            ss[t] += a;
            __syncthreads();
        }
        if (t < nb) { sb[t] = ss[t] - v; lcur[t] = ss[t] - v; }
    }
    __syncthreads();
#pragma unroll
    for (int k = 0; k < 16; ++k) {
        if (pb[k] >= 0) {
            int pos = atomicAdd(&lcur[pb[k]], 1);
            spair[pos] = pv[k];
            sbkt[pos] = (unsigned short)pb[k];
        }
    }
    __syncthreads();
    if (t < nb && h[t] > 0) goff[t] = atomicAdd(&bcur[t], h[t]);
    __syncthreads();
    int M = min(CHUNK, E - e0);
    for (int i = t; i < M; i += 256) {
        int b = sbkt[i];
        ebin[goff[b] + i - sb[b]] = spair[i];
    }
}

// ---------------------------------------------------------------------------
// Fused compose+project. Each block redundantly computes the 516-float
// composite (whole dense net collapsed to [64x8] + 4 consts) into LDS,
// then projects its 256 nodes: ac=(a0,a1,c0,c1) [1.6 MB, the only per-edge
// operand], bd = self terms + bias consts.
// ---------------------------------------------------------------------------
__global__ __launch_bounds__(256) void k_projectc(
    const float4* __restrict__ x4,
    const float* __restrict__ Wl1, const float* __restrict__ bl1,
    const float* __restrict__ Wr1, const float* __restrict__ Wl2,
    const float* __restrict__ Wr2,
    float4* __restrict__ ac, float4* __restrict__ bd, int N) {
    __shared__ float sc[516];
    int t = threadIdx.x;
    {
        int m = t >> 6;      // 0:Mp 1:Np 2:Mq 3:Nq
        int k = t & 63;
        const float* W1 = (m == 0 || m == 2) ? Wl1 : Wr1;
        const float* W2 = (m < 2) ? Wl2 : Wr2;
        float a0 = 0.f, a1 = 0.f;
        for (int o = 0; o < NF; ++o) {
            float w1 = W1[o * NF + k];
            a0 = fmaf(W2[o], w1, a0);
            a1 = fmaf(W2[NF + o], w1, a1);
        }
        sc[k * 8 + 2 * m]     = a0;
        sc[k * 8 + 2 * m + 1] = a1;
        if (t < 4) {
            const float* W2c = (t < 2) ? Wl2 : Wr2;
            int c = t & 1;
            float s = 0.f;
            for (int o = 0; o < NF; ++o) s = fmaf(bl1[o], W2c[c * NF + o], s);
            sc[512 + t] = s;
        }
    }
    __syncthreads();
    int node = blockIdx.x * 256 + t;
    if (node >= N) return;
    float a0 = 0.f, a1 = 0.f, b0 = 0.f, b1 = 0.f;
    float c0 = 0.f, c1 = 0.f, d0 = 0.f, d1 = 0.f;
#pragma unroll
    for (int kk = 0; kk < 16; ++kk) {
        float4 xv = x4[(size_t)node * 16 + kk];
        const float xs[4] = {xv.x, xv.y, xv.z, xv.w};
#pragma unroll
        for (int j = 0; j < 4; ++j) {
            float xj = xs[j];
            const float* c8 = sc + (kk * 4 + j) * 8;   // uniform addr: bcast
            a0 = fmaf(xj, c8[0], a0); a1 = fmaf(xj, c8[1], a1);
            b0 = fmaf(xj, c8[2], b0); b1 = fmaf(xj, c8[3], b1);
            c0 = fmaf(xj, c8[4], c0); c1 = fmaf(xj, c8[5], c1);
            d0 = fmaf(xj, c8[6], d0); d1 = fmaf(xj, c8[7], d1);
        }
    }
    ac[node] = make_float4(a0, a1, c0, c1);
    bd[node] = make_float4(b0 + sc[512], b1 + sc[513],
                           d0 + sc[514], d1 + sc[515]);
}

// ---------------------------------------------------------------------------
// Fused per-bucket sort + layer-1 aggregation. Sort the bucket's edges into
// LDS (global fallback if cnt > CAP), write srt as a COALESCED copy (for
// agg2), emit deg/base, then aggregate ac[src] per node straight from LDS —
// all XCD-local, zero float atomics.
// ---------------------------------------------------------------------------
__global__ __launch_bounds__(512) void kb_sortagg(
    const int* __restrict__ ebin, const int* __restrict__ bbase,
    const float4* __restrict__ ac, const float4* __restrict__ bd,
    int* __restrict__ srt, int* __restrict__ deg, int* __restrict__ base,
    float2* __restrict__ p, float2* __restrict__ q, int N) {
    __shared__ int h[BSZ], lb[BSZ], ss[BSZ];
    __shared__ int sp[CAP];
    int b = blockIdx.x;
    int t = threadIdx.x;
    int g0 = bbase[b];
    int cnt = bbase[b + 1] - g0;
    int n0 = b << SHIFT;
    int nn = min(BSZ, N - n0);
    h[t] = 0;
    __syncthreads();
    for (int i = t; i < cnt; i += 512)
        atomicAdd(&h[ebin[g0 + i] >> 17], 1);
    __syncthreads();
    int mydeg = h[t];
    ss[t] = mydeg;
    __syncthreads();
    for (int off = 1; off < 512; off <<= 1) {
        int a = (t >= off) ? ss[t - off] : 0;
        __syncthreads();
        ss[t] += a;
        __syncthreads();
    }
    lb[t] = ss[t] - mydeg;                  // exclusive within bucket
    if (t < nn) { deg[n0 + t] = mydeg; base[n0 + t] = g0 + lb[t]; }
    __syncthreads();
    h[t] = 0;                               // reuse as per-node cursor
    __syncthreads();

    if (cnt <= CAP) {
        // ---- LDS-resident path ----
        for (int i = t; i < cnt; i += 512) {
            int pv = ebin[g0 + i];
            int dl = pv >> 17;
            int pos = atomicAdd(&h[dl], 1);
            sp[lb[dl] + pos] = pv & 0x1FFFF;
        }
        __syncthreads();
        for (int i = t; i < cnt; i += 512)  // coalesced srt writeout
            srt[g0 + i] = sp[i];
        if (t < nn) {
            int s0 = lb[t];
            float a0 = 0.f, a1 = 0.f, c0 = 0.f, c1 = 0.f;
            for (int j = 0; j < mydeg; ++j) {
                float4 v = ac[sp[s0 + j]];
                a0 += v.x; a1 += v.y; c0 += v.z; c1 += v.w;
            }
            float inv = 1.f / (float)(mydeg > 1 ? mydeg : 1);
            float4 bv = bd[n0 + t];
            p[n0 + t] = make_float2(fmaf(a0, inv, bv.x), fmaf(a1, inv, bv.y));
            q[n0 + t] = make_float2(fmaf(c0, inv, bv.z), fmaf(c1, inv, bv.w));
        }
    } else {
        // ---- global fallback (correct for any skew) ----
        for (int i = t; i < cnt; i += 512) {
            int pv = ebin[g0 + i];
            int dl = pv >> 17;
            int pos = atomicAdd(&h[dl], 1);
            srt[g0 + lb[dl] + pos] = pv & 0x1FFFF;
        }
        __syncthreads();
        if (t < nn) {
            int s0 = g0 + lb[t];
            float a0 = 0.f, a1 = 0.f, c0 = 0.f, c1 = 0.f;
            for (int j = 0; j < mydeg; ++j) {
                float4 v = ac[srt[s0 + j]];
                a0 += v.x; a1 += v.y; c0 += v.z; c1 += v.w;
            }
            float inv = 1.f / (float)(mydeg > 1 ? mydeg : 1);
            float4 bv = bd[n0 + t];
            p[n0 + t] = make_float2(fmaf(a0, inv, bv.x), fmaf(a1, inv, bv.y));
            q[n0 + t] = make_float2(fmaf(c0, inv, bv.z), fmaf(c1, inv, bv.w));
        }
    }
}

// ---------------------------------------------------------------------------
// Layer-2 aggregation + epilogue, ATOMIC-FREE: 2 lanes per node over p,
// pair shfl-reduce, lane 0 does log_softmax and writes out.
// ---------------------------------------------------------------------------
__global__ __launch_bounds__(256) void k_agg2c(
    const int* __restrict__ srt, const int* __restrict__ base,
    const int* __restrict__ deg, const float2* __restrict__ p,
    const float2* __restrict__ q, const float* __restrict__ bl2,
    float2* __restrict__ out, int N) {
    int tid = blockIdx.x * 256 + threadIdx.x;
    int node = tid >> 1, c = tid & 1;
    if (node >= N) return;
    int b0 = base[node];
    int dg = deg[node];
    float s0 = 0.f, s1 = 0.f;
    for (int j = c; j < dg; j += 2) {
        float2 v = p[srt[b0 + j]];
        s0 += v.x; s1 += v.y;
    }
    s0 += __shfl_xor(s0, 1, 64);
    s1 += __shfl_xor(s1, 1, 64);
    if (c == 0) {
        float inv = 1.f / (float)(dg > 1 ? dg : 1);
        float2 qv = q[node];
        float l0 = fmaf(s0, inv, bl2[0] + qv.x);
        float l1 = fmaf(s1, inv, bl2[1] + qv.y);
        float m = fmaxf(l0, l1);
        float lse = m + logf(expf(l0 - m) + expf(l1 - m));
        out[node] = make_float2(l0 - lse, l1 - lse);
    }
}

// ---------------------------------------------------------------------------
extern "C" void kernel_launch(void* const* d_in, const int* in_sizes, int n_in,
                              void* d_out, int out_size, void* d_ws, size_t ws_size,
                              hipStream_t stream) {
    const float* x   = (const float*)d_in[0];
    const int*   ei  = (const int*)d_in[1];
    const float* Wl1 = (const float*)d_in[2];
    const float* bl1 = (const float*)d_in[3];
    const float* Wr1 = (const float*)d_in[4];
    const float* Wl2 = (const float*)d_in[5];
    const float* bl2 = (const float*)d_in[6];
    const float* Wr2 = (const float*)d_in[7];
    float* out = (float*)d_out;

    int N = in_sizes[0] / NF;     // 100000 (< 2^17 required by packing)
    int E = in_sizes[1] / 2;      // 1600000
    int nb = (N + BSZ - 1) >> SHIFT;   // 196 buckets

    // Workspace: ints [ebin:E | srt:E | deg:N | base:N | bhist:256 |
    //                  bbase:257 | bcur:256 | pad:3]
    //            floats [ac:4N | bd:4N | p:2N | q:2N]
    int* wsi    = (int*)d_ws;
    int* ebin   = wsi;
    int* srt    = wsi + E;
    int* deg    = wsi + 2 * (size_t)E;
    int* base   = deg + N;
    int* bhist  = base + N;
    int* bbase  = bhist + 256;
    int* bcur   = bbase + 257;
    float* ac   = (float*)(bcur + 256 + 3);   // 16B-aligned
    float* bd   = ac + 4 * (size_t)N;
    float* p    = bd + 4 * (size_t)N;
    float* q    = p + 2 * (size_t)N;

    hipMemsetAsync(bhist, 0, 256 * sizeof(int), stream);

    kb_hist<<<256, 256, 0, stream>>>(ei, bhist, E, nb);
    kb_scan<<<1, 256, 0, stream>>>(bhist, bbase, bcur, nb);
    k_projectc<<<(N + 255) / 256, 256, 0, stream>>>((const float4*)x,
                                                    Wl1, bl1, Wr1, Wl2, Wr2,
                                                    (float4*)ac, (float4*)bd, N);
    kb_bin <<<(E + CHUNK - 1) / CHUNK, 256, 0, stream>>>(ei, bcur, ebin, E, nb);
    kb_sortagg<<<nb, 512, 0, stream>>>(ebin, bbase, (const float4*)ac,
                                       (const float4*)bd, srt, deg, base,
                                       (float2*)p, (float2*)q, N);
    k_agg2c<<<(2 * N + 255) / 256, 256, 0, stream>>>(srt, base, deg,
                                                     (const float2*)p,
                                                     (const float2*)q, bl2,
                                                     (float2*)out, N);
}